// Round 4
// baseline (267.991 us; speedup 1.0000x reference)
//
#include <hip/hip_runtime.h>
#include <cmath>

// Outputs concatenated flat (all float32):
//   [0)      N*N*3 : dxyz_m
//   [N*N*3)  N*N   : buckets
//   [N*N*4)  N*N   : dscanid
//   [N*N*5)  N*N   : mask

typedef float vf4 __attribute__((ext_vector_type(4))); // native vector: OK for nontemporal builtin

__device__ __forceinline__ float bucket_base(float v) {
    // x = v / RES (RES=0.5 -> exact *2)
    const float x  = v * 2.0f;
    const float xa = fabsf(x);
    if (xa <= 2.0f) {
        // round-half-to-even like jnp.round
        return 8.0f + rintf(x);
    }
    // log path only when needed (xa>2 => x != 0)
    const float lr = logf(fmaxf(xa, 1e-6f) * 0.5f) / 2.0794415416798357f; // /log(8)
    const float sup = fminf(rintf(2.0f - 6.0f * lr), 8.0f);
    return 8.0f + ((x > 0.0f) ? sup : -sup);
}

__device__ __forceinline__ void nt_store4(float* p, float a, float b, float c, float d) {
    vf4 v; v.x = a; v.y = b; v.z = c; v.w = d;
    __builtin_nontemporal_store(v, reinterpret_cast<vf4*>(p)); // global_store_dwordx4 nt
}

__global__ __launch_bounds__(256) void pair_kernel(
    const float* __restrict__ xyz, const int* __restrict__ grid,
    float* __restrict__ out, int N) {
#pragma clang fp contract(off)
    const int jq = blockIdx.x * blockDim.x + threadIdx.x; // quad-of-j index
    const int j0 = jq << 2;
    const int i  = blockIdx.y;
    if (j0 >= N) return;

    // i-side (wave-uniform -> scalar)
    const float xi = xyz[3 * i + 0];
    const float yi = xyz[3 * i + 1];
    const float zi = xyz[3 * i + 2];
    const int bat_i = grid[5 * i + 0];
    const int blk_i = grid[5 * i + 1];
    const int c0i = grid[5 * i + 2];
    const int c1i = grid[5 * i + 3];
    const int c2i = grid[5 * i + 4];
    const int xci = (int)ceilf(xi / 3.0f);
    const int yci = (int)ceilf(yi / 3.0f);
    const int scan_i = blk_i >> 1;

    // j-side: vectorized loads (j0 % 4 == 0 -> 16B aligned)
    const float4* pv = reinterpret_cast<const float4*>(xyz + (size_t)3 * j0);
    const float4 p0 = pv[0], p1 = pv[1], p2 = pv[2];
    const int4* gv = reinterpret_cast<const int4*>(grid + (size_t)5 * j0);
    const int4 g0 = gv[0], g1 = gv[1], g2 = gv[2], g3 = gv[3], g4 = gv[4];

    const float jx[4]  = {p0.x, p0.w, p1.z, p2.y};
    const float jy[4]  = {p0.y, p1.x, p1.w, p2.z};
    const float jz[4]  = {p0.z, p1.y, p2.x, p2.w};
    const int   jbat[4] = {g0.x, g1.y, g2.z, g3.w};
    const int   jblk[4] = {g0.y, g1.z, g2.w, g4.x};
    const int   jc0[4]  = {g0.z, g1.w, g3.x, g4.y};
    const int   jc1[4]  = {g0.w, g2.x, g3.y, g4.z};
    const int   jc2[4]  = {g1.x, g2.y, g3.z, g4.w};

    float dxm[4], dym[4], dzm[4];
    bool  mk[4];
    bool  any = false;
#pragma unroll
    for (int k = 0; k < 4; ++k) {
        const float dx = xi - jx[k];
        const float dy = yi - jy[k];
        const float dz = zi - jz[k];
        const bool batch_eq = (bat_i == jbat[k]);
        const bool block_le = (blk_i <= jblk[k]);
        const int  cadj = max(max(abs(c0i - jc0[k]), abs(c1i - jc1[k])),
                              abs(c2i - jc2[k]));
        const bool forcekeep = (cadj <= 1) && (blk_i == jblk[k]);
        const int xcj = (int)ceilf(jx[k] / 3.0f);
        const int ycj = (int)ceilf(jy[k] / 3.0f);
        const bool keep_coarse = max(abs(xci - xcj), abs(yci - ycj)) <= 1;
        const float d2 = dx * dx + dy * dy + dz * dz; // contract(off): matches ref
        const bool keepr = (d2 <= 9.0f);
        const bool m = batch_eq && block_le &&
                       (forcekeep || keep_coarse) && (forcekeep || keepr);
        mk[k] = m;
        any |= m;
        dxm[k] = m ? dx : 0.0f;
        dym[k] = m ? dy : 0.0f;
        dzm[k] = m ? dz : 0.0f;
    }

    const size_t NN   = (size_t)N * (size_t)N;
    const size_t base = (size_t)i * (size_t)N + (size_t)j0;
    float* o_dxyz = out + 3 * base;
    float* o_bkt  = out + NN * 3 + base;
    float* o_dsc  = out + NN * 4 + base;
    float* o_msk  = out + NN * 5 + base;

    // Wave-uniform fast path: nothing kept anywhere in this wave -> pure zeros.
    if (__ballot(any ? 1 : 0) == 0ULL) {
        nt_store4(o_dxyz + 0, 0.0f, 0.0f, 0.0f, 0.0f);
        nt_store4(o_dxyz + 4, 0.0f, 0.0f, 0.0f, 0.0f);
        nt_store4(o_dxyz + 8, 0.0f, 0.0f, 0.0f, 0.0f);
        nt_store4(o_bkt, 0.0f, 0.0f, 0.0f, 0.0f);
        nt_store4(o_dsc, 0.0f, 0.0f, 0.0f, 0.0f);
        nt_store4(o_msk, 0.0f, 0.0f, 0.0f, 0.0f);
        return;
    }

    float bf[4], df[4], mf[4];
#pragma unroll
    for (int k = 0; k < 4; ++k) {
        if (mk[k]) {
            const float b0 = bucket_base(dxm[k]);
            const float b1 = bucket_base(dym[k]);
            const float b2 = bucket_base(dzm[k]);
            const float bsum = (289.0f * b0 + 17.0f * b1) + b2; // exact small ints
            bf[k] = (float)(int)bsum;
            df[k] = (float)((jblk[k] >> 1) - scan_i);
            mf[k] = 1.0f;
        } else {
            bf[k] = 0.0f; df[k] = 0.0f; mf[k] = 0.0f;
        }
    }

    nt_store4(o_dxyz + 0, dxm[0], dym[0], dzm[0], dxm[1]);
    nt_store4(o_dxyz + 4, dym[1], dzm[1], dxm[2], dym[2]);
    nt_store4(o_dxyz + 8, dzm[2], dxm[3], dym[3], dzm[3]);
    nt_store4(o_bkt, bf[0], bf[1], bf[2], bf[3]);
    nt_store4(o_dsc, df[0], df[1], df[2], df[3]);
    nt_store4(o_msk, mf[0], mf[1], mf[2], mf[3]);
}

extern "C" void kernel_launch(void* const* d_in, const int* in_sizes, int n_in,
                              void* d_out, int out_size, void* d_ws, size_t ws_size,
                              hipStream_t stream) {
    const float* xyz  = (const float*)d_in[0];
    const int*   grid = (const int*)d_in[1];
    float*       out  = (float*)d_out;
    const int N = in_sizes[0] / 3; // xyz is (N,3); N=3072, divisible by 4

    const int BLOCK = 256;               // 256 threads x 4 j = 1024 j per block
    const int jquads = N / 4;
    dim3 gdim((jquads + BLOCK - 1) / BLOCK, N, 1);
    pair_kernel<<<gdim, dim3(BLOCK, 1, 1), 0, stream>>>(xyz, grid, out, N);
}